// Round 1
// baseline (6380.729 us; speedup 1.0000x reference)
//
#include <hip/hip_runtime.h>

#define NENT 40000
#define NB 128
#define NQ 24
#define NOPS 12
#define EPO 300000
#define NTOT (NOPS * EPO)
#define NRANK 3
#define NPASS 8
#define CP 16       // batch columns per pass
#define ECAP 160    // ELL row capacity (Poisson(90) max over 40K rows << 160)

typedef float v4f __attribute__((ext_vector_type(4)));

__device__ __forceinline__ v4f shfl_xor4(v4f x, int m) {
    v4f r;
    r.x = __shfl_xor(x.x, m);
    r.y = __shfl_xor(x.y, m);
    r.z = __shfl_xor(x.z, m);
    r.w = __shfl_xor(x.w, m);
    return r;
}

__device__ __forceinline__ bool bittest(const unsigned* bm, int i) {
    return (bm[i >> 5] >> (i & 31)) & 1u;
}

// ---------------- bitmaps: heads and heads ∪ N_out(heads) ----------------
__global__ void headmark_kernel(const int* __restrict__ heads, unsigned* __restrict__ bmH,
                                unsigned* __restrict__ bm2) {
    int h = heads[threadIdx.x];
    atomicOr(&bmH[h >> 5], 1u << (h & 31));
    atomicOr(&bm2[h >> 5], 1u << (h & 31));
}

__global__ void mark2_kernel(const int* __restrict__ src, const int* __restrict__ dst,
                             const unsigned* __restrict__ bmH, unsigned* __restrict__ bm2) {
    int i = blockIdx.x * 256 + threadIdx.x;
    if (i < NTOT) {
        int s = src[i];
        if (bittest(bmH, s)) {
            int d = dst[i];
            atomicOr(&bm2[d >> 5], 1u << (d & 31));
        }
    }
}

// ---------------- single-pass ELL build: dst always; src gated on bm2 ----------------
__global__ void build_ell_kernel(const int* __restrict__ src, const int* __restrict__ dst,
                                 const float* __restrict__ val, const unsigned* __restrict__ bm2,
                                 int* __restrict__ fillD, int* __restrict__ fillS,
                                 int2* __restrict__ eD, int2* __restrict__ eS) {
    int i = blockIdx.x * 256 + threadIdx.x;
    if (i >= NTOT) return;
    int s = src[i], d = dst[i];
    int op = i / EPO;   // compile-time magic-mul
    int v = __float_as_int(val[i]);
    int pd = atomicAdd(&fillD[d], 1);
    eD[(size_t)d * ECAP + pd] = make_int2(s | (op << 16), v);
    if (bittest(bm2, s)) {
        int ps = atomicAdd(&fillS[s], 1);
        eS[(size_t)s * ECAP + ps] = make_int2(d | (op << 16), v);
    }
}

// ---------------- LSTM (deduped over 24 distinct query values) ----------------
__global__ void zxq_kernel(const float* __restrict__ emb,
                           const float* __restrict__ Wih_f, const float* __restrict__ bih_f,
                           const float* __restrict__ bhh_f,
                           const float* __restrict__ Wih_b, const float* __restrict__ bih_b,
                           const float* __restrict__ bhh_b,
                           float* __restrict__ zxq) {
    int combo = blockIdx.x / NQ;
    int q = blockIdx.x % NQ;
    int dir = combo / 3, r = combo % 3;
    const float* Wih = (dir ? Wih_b : Wih_f) + r * 512 * 128;
    const float* bih = (dir ? bih_b : bih_f) + r * 512;
    const float* bhh = (dir ? bhh_b : bhh_f) + r * 512;
    __shared__ float x[128];
    int u = threadIdx.x;
    x[u] = emb[q * 128 + u];
    __syncthreads();
    const float* W0p = Wih + u * 128;
    const float* W1p = Wih + (128 + u) * 128;
    const float* W2p = Wih + (256 + u) * 128;
    const float* W3p = Wih + (384 + u) * 128;
    float a0 = 0.f, a1 = 0.f, a2 = 0.f, a3 = 0.f;
    for (int d = 0; d < 128; ++d) {
        float xv = x[d];
        a0 = fmaf(xv, W0p[d], a0);
        a1 = fmaf(xv, W1p[d], a1);
        a2 = fmaf(xv, W2p[d], a2);
        a3 = fmaf(xv, W3p[d], a3);
    }
    float* o = zxq + (size_t)(combo * NQ + q) * 512;
    o[u]       = a0 + bih[u]       + bhh[u];
    o[128 + u] = a1 + bih[128 + u] + bhh[128 + u];
    o[256 + u] = a2 + bih[256 + u] + bhh[256 + u];
    o[384 + u] = a3 + bih[384 + u] + bhh[384 + u];
}

__global__ void lstmq_kernel(const float* __restrict__ Whh_f, const float* __restrict__ Whh_b,
                             const float* __restrict__ zxq, float* __restrict__ hq) {
    int combo = blockIdx.x / NQ;
    int q = blockIdx.x % NQ;
    int dir = combo / 3, r = combo % 3;
    const float* Whh = (dir ? Whh_b : Whh_f) + r * 512 * 128;
    __shared__ float h[128];
    int u = threadIdx.x;
    const float* z = zxq + (size_t)(combo * NQ + q) * 512;
    float zi0 = z[u], zf0 = z[128 + u], zg0 = z[256 + u], zo0 = z[384 + u];
    const float* Wi = Whh + u * 128;
    const float* Wf = Whh + (128 + u) * 128;
    const float* Wg = Whh + (256 + u) * 128;
    const float* Wo = Whh + (384 + u) * 128;
    float c = 0.f;
    h[u] = 0.f;
    for (int s = 0; s < 3; ++s) {
        __syncthreads();
        float a0 = 0.f, a1 = 0.f, a2 = 0.f, a3 = 0.f;
        for (int d = 0; d < 128; ++d) {
            float hv = h[d];
            a0 = fmaf(hv, Wi[d], a0);
            a1 = fmaf(hv, Wf[d], a1);
            a2 = fmaf(hv, Wg[d], a2);
            a3 = fmaf(hv, Wo[d], a3);
        }
        float ig = 1.f / (1.f + expf(-(zi0 + a0)));
        float fg = 1.f / (1.f + expf(-(zf0 + a1)));
        float gg = tanhf(zg0 + a2);
        float og = 1.f / (1.f + expf(-(zo0 + a3)));
        c = fg * c + ig * gg;
        float hn = og * tanhf(c);
        __syncthreads();
        h[u] = hn;
        hq[(size_t)((combo * 3 + s) * NQ + q) * 128 + u] = hn;
    }
}

__global__ void attnq_kernel(const float* __restrict__ hq, const float* __restrict__ W0,
                             const float* __restrict__ b0, float* __restrict__ attnq) {
    int r = blockIdx.x / 3, t = blockIdx.x % 3;
    __shared__ float W0s[256 * 13];
    for (int idx = threadIdx.x; idx < 256 * 13; idx += 32) W0s[idx] = W0[idx];
    __syncthreads();
    int q = threadIdx.x;
    if (q >= NQ) return;
    float acc[13];
    for (int k = 0; k < 13; ++k) acc[k] = b0[k];
    const float* hf = hq + (size_t)(((0 * 3 + r) * 3 + t) * NQ + q) * 128;
    const float* hb = hq + (size_t)(((1 * 3 + r) * 3 + (2 - t)) * NQ + q) * 128;
    for (int u = 0; u < 128; ++u) {
        float v = hf[u];
        for (int k = 0; k < 13; ++k) acc[k] = fmaf(v, W0s[u * 13 + k], acc[k]);
    }
    for (int u = 0; u < 128; ++u) {
        float v = hb[u];
        for (int k = 0; k < 13; ++k) acc[k] = fmaf(v, W0s[(128 + u) * 13 + k], acc[k]);
    }
    float m = acc[0];
    for (int k = 1; k < 13; ++k) m = fmaxf(m, acc[k]);
    float e[13];
    float sum = 0.f;
    for (int k = 0; k < 13; ++k) { e[k] = expf(acc[k] - m); sum += e[k]; }
    float inv = 1.f / sum;
    float* ao = attnq + (size_t)(r * 3 + t) * 13 * NQ;
    for (int k = 0; k < 13; ++k) ao[k * NQ + q] = e[k] * inv;
}

__global__ void expand_kernel(const int* __restrict__ queries, const float* __restrict__ attnq,
                              float* __restrict__ attn) {
    __shared__ int qs[128];
    if (threadIdx.x < 128) qs[threadIdx.x] = queries[threadIdx.x];
    __syncthreads();
    for (int idx = threadIdx.x; idx < 9 * 13 * 128; idx += 256) {
        int b = idx & 127, kk = idx >> 7;
        attn[idx] = attnq[kk * NQ + qs[b]];
    }
}

// ---------------- steps 0+1, sparse expansion over ELL-S; writes pass-major mem[r][p][j][c] ----------------
// 256 threads, 8-lane groups per source entry; z-chunked grid for occupancy.
__global__ void fused01_kernel(const int* __restrict__ heads, const float* __restrict__ attn,
                               const int* __restrict__ fillS, const int2* __restrict__ eS,
                               float* __restrict__ mem2) {
    int r = blockIdx.y;
    int b = blockIdx.x;
    int chunk = blockIdx.z;   // 0..1
    __shared__ float c0s[13], c1s[13];
    if (threadIdx.x < 13) {
        c0s[threadIdx.x] = attn[(size_t)((r * 3 + 0) * 13 + threadIdx.x) * 128 + b];
        c1s[threadIdx.x] = attn[(size_t)((r * 3 + 1) * 13 + threadIdx.x) * 128 + b];
    }
    __syncthreads();
    int h = heads[b];
    int lenH = fillS[h];
    float* mem = mem2 + ((size_t)(r * NPASS + (b >> 4)) * NENT) * CP + (b & 15);
    int g = threadIdx.x >> 3, lane8 = threadIdx.x & 7;   // 32 groups of 8 lanes
    for (int ent = g + chunk * 32; ent < lenH + 1; ent += 64) {
        int i; float wv;
        if (ent == 0) { i = h; wv = c0s[12]; }
        else {
            int2 e = eS[(size_t)h * ECAP + ent - 1];
            i = e.x & 0xFFFF;
            wv = __int_as_float(e.y) * c0s[e.x >> 16];
        }
        if (lane8 == 0) atomicAdd(&mem[(size_t)i * CP], c1s[12] * wv);
        int lenI = fillS[i];
        const int2* ei = eS + (size_t)i * ECAP;
        for (int f = lane8; f < lenI; f += 8) {
            int2 e2 = ei[f];
            atomicAdd(&mem[(size_t)(e2.x & 0xFFFF) * CP],
                      __int_as_float(e2.y) * c1s[e2.x >> 16] * wv);
        }
    }
}

// ---------------- step 2: dense gather; LDS-staged edges + 3-deep pipelined gathers ----------------
struct Stage { v4f g0, g1, g2, g3; float w0, w1, w2, w3; int o0, o1, o2, o3; };

#define ISSUE_ONE(G, W, O, LT, RT, bi) { \
    bool m = (bi) < (LT); \
    int2 e = eL[RT][m ? (bi) : 0]; \
    int ex = m ? e.x : 0; \
    W = m ? __int_as_float(e.y) : 0.f; \
    O = ex >> 16; \
    G = *(const v4f*)(inr + (size_t)(ex & 0xFFFF) * CP + cq4); }

#define ISSUE(S, bb) { int bi = (bb) + slot; \
    ISSUE_ONE(S.g0, S.w0, S.o0, l0, rw + 0, bi) \
    ISSUE_ONE(S.g1, S.w1, S.o1, l1, rw + 1, bi) \
    ISSUE_ONE(S.g2, S.w2, S.o2, l2, rw + 2, bi) \
    ISSUE_ONE(S.g3, S.w3, S.o3, l3, rw + 3, bi) }

#define CONSUME(S) { \
    { v4f cc = *(const v4f*)&cs[S.o0 * 20 + cq4]; acc0 += (S.w0 * cc) * S.g0; } \
    { v4f cc = *(const v4f*)&cs[S.o1 * 20 + cq4]; acc1 += (S.w1 * cc) * S.g1; } \
    { v4f cc = *(const v4f*)&cs[S.o2 * 20 + cq4]; acc2 += (S.w2 * cc) * S.g2; } \
    { v4f cc = *(const v4f*)&cs[S.o3 * 20 + cq4]; acc3 += (S.w3 * cc) * S.g3; } }

#define REDUCE_ROW(A, T) { \
    v4f red = A; \
    red += shfl_xor4(red, 4); \
    red += shfl_xor4(red, 8); \
    red += shfl_xor4(red, 16); \
    red += shfl_xor4(red, 32); \
    if (slot == 0) { \
        int j = jw + (T); \
        v4f mi = *(const v4f*)(inr + (size_t)j * CP + cq4); \
        v4f res = cid * mi + red; \
        *(v4f*)(outr + (size_t)j * CP + cq4) = res; \
        rsum += res; \
    } }

__global__ __launch_bounds__(256, 4) void dense_kernel(const float* __restrict__ attn,
                                                       const int* __restrict__ fillD,
                                                       const int2* __restrict__ edgesD,
                                                       const float* __restrict__ in,
                                                       float* __restrict__ out,
                                                       float* __restrict__ normv) {
    int p = blockIdx.x;   // pass = XCD (linear-id % 8 round-robin)
    int r = blockIdx.z;
    __shared__ __align__(16) float cs[13 * 20];   // stride 20 floats: rows 16B-aligned
    __shared__ float npart[4][16];
    __shared__ __align__(16) int2 eL[16][ECAP];   // 20.5 KB staged edge lists
    int tid = threadIdx.x;
    int wave = tid >> 6, lane = tid & 63;

    // async stage: 16 ELL rows = 20480 contiguous bytes, direct global->LDS, width 16
    {
        const char* gp = (const char*)(edgesD + (size_t)(blockIdx.y * 16) * ECAP);
        char* lp = (char*)&eL[0][0];
#pragma unroll
        for (int k = 0; k < 5; ++k) {
            int off = (wave * 5 + k) * 1024;
            __builtin_amdgcn_global_load_lds(
                (const __attribute__((address_space(1))) unsigned*)(gp + off + lane * 16),
                (__attribute__((address_space(3))) unsigned*)(lp + off),
                16, 0, 0);
        }
    }
    if (tid < 13 * 16) {
        int op = tid >> 4, c0 = tid & 15;
        cs[op * 20 + c0] = attn[(size_t)((r * 3 + 2) * 13 + op) * 128 + p * CP + c0];
    }
    int slot = lane >> 2;        // 16 edge slots
    int cq4 = (lane & 3) * 4;    // 4 cols per lane
    int rw = wave * 4;           // this wave's first LDS row
    int jw = blockIdx.y * 16 + rw;
    int l0 = fillD[jw], l1 = fillD[jw + 1], l2 = fillD[jw + 2], l3 = fillD[jw + 3];
    int maxlen = max(max(l0, l1), max(l2, l3));
    const float* inr = in + (size_t)(r * NPASS + p) * NENT * CP;
    float* outr = out + (size_t)(r * NPASS + p) * NENT * CP;
    __syncthreads();   // drains global_load_lds (vmcnt) + cs writes

    v4f acc0 = (v4f)0.f, acc1 = (v4f)0.f, acc2 = (v4f)0.f, acc3 = (v4f)0.f;
    Stage SA, SB, SC;
    // 3-deep software pipeline: 12 gathers continuously in flight per wave
    ISSUE(SA, 0)
    ISSUE(SB, 16)
    ISSUE(SC, 32)
    for (int base = 48; base < maxlen; base += 48) {
        CONSUME(SA) ISSUE(SA, base)
        CONSUME(SB) ISSUE(SB, base + 16)
        CONSUME(SC) ISSUE(SC, base + 32)
    }
    CONSUME(SA)
    CONSUME(SB)
    CONSUME(SC)

    v4f cid = *(const v4f*)&cs[12 * 20 + cq4];
    v4f rsum = (v4f)0.f;
    REDUCE_ROW(acc0, 0)
    REDUCE_ROW(acc1, 1)
    REDUCE_ROW(acc2, 2)
    REDUCE_ROW(acc3, 3)
    if (slot == 0) *(v4f*)&npart[wave][cq4] = rsum;
    __syncthreads();
    if (tid < 16) {
        float s = npart[0][tid] + npart[1][tid] + npart[2][tid] + npart[3][tid];
        atomicAdd(&normv[r * 128 + p * CP + tid], s);
    }
}

// ---------------- epilogue ----------------
__global__ void rnorm_kernel(const float* __restrict__ normv, float* __restrict__ rnormv) {
    int i = threadIdx.x;
    rnormv[i] = 1.f / fmaxf(normv[i], 1e-20f);
}

__global__ void final_kernel(const float* __restrict__ mem3, const float* __restrict__ rnormv,
                             float* __restrict__ out) {
    __shared__ float tile[32 * 129];
    __shared__ float rn[384];
    for (int idx = threadIdx.x; idx < 384; idx += 256) rn[idx] = rnormv[idx];
    __syncthreads();
    int j0 = blockIdx.x * 32;
    for (int p = 0; p < NPASS; ++p) {
        for (int it = 0; it < 2; ++it) {
            int lin = it * 256 + threadIdx.x;
            int jj = lin >> 4, c = lin & 15;
            int b = p * CP + c;
            float s = 0.f;
            for (int r = 0; r < 3; ++r)
                s += mem3[((size_t)(r * NPASS + p) * NENT + j0 + jj) * CP + c] * rn[r * 128 + b];
            tile[jj * 129 + b] = s;
        }
    }
    __syncthreads();
    for (int it = 0; it < 16; ++it) {
        int lin = it * 256 + threadIdx.x;
        int b = lin >> 5, jj = lin & 31;
        out[(size_t)b * NENT + j0 + jj] = tile[jj * 129 + b];
    }
}

extern "C" void kernel_launch(void* const* d_in, const int* in_sizes, int n_in,
                              void* d_out, int out_size, void* d_ws, size_t ws_size,
                              hipStream_t stream) {
    const int*   queries  = (const int*)d_in[0];
    const int*   heads    = (const int*)d_in[1];
    const int*   edge_src = (const int*)d_in[2];
    const int*   edge_dst = (const int*)d_in[3];
    const float* edge_val = (const float*)d_in[4];
    const float* emb      = (const float*)d_in[5];
    const float* Wih_f    = (const float*)d_in[6];
    const float* Whh_f    = (const float*)d_in[7];
    const float* bih_f    = (const float*)d_in[8];
    const float* bhh_f    = (const float*)d_in[9];
    const float* Wih_b    = (const float*)d_in[10];
    const float* Whh_b    = (const float*)d_in[11];
    const float* bih_b    = (const float*)d_in[12];
    const float* bhh_b    = (const float*)d_in[13];
    const float* W0       = (const float*)d_in[14];
    const float* b0       = (const float*)d_in[15];
    float* out = (float*)d_out;

    char* w = (char*)d_ws;
    size_t off = 0;
    auto alloc = [&](size_t bytes) -> void* {
        off = (off + 255) & ~(size_t)255;
        void* p = w + off;
        off += bytes;
        return p;
    };
    float* attnq  = (float*)alloc((size_t)9 * 13 * NQ * sizeof(float));
    float* attn   = (float*)alloc((size_t)9 * 13 * 128 * sizeof(float));
    float* zxq    = (float*)alloc((size_t)6 * NQ * 512 * sizeof(float));
    float* hq     = (float*)alloc((size_t)6 * 3 * NQ * 128 * sizeof(float));
    // meta block (single memset): bmH | bm2 | fillD | fillS
    unsigned* bmH = (unsigned*)alloc((2 * 1250 + 2 * NENT) * sizeof(int));
    unsigned* bm2 = bmH + 1250;
    int* fillD    = (int*)(bm2 + 1250);
    int* fillS    = fillD + NENT;
    int2*  eD     = (int2*)alloc((size_t)NENT * ECAP * sizeof(int2));
    float* mem2   = (float*)alloc((size_t)NRANK * NENT * NB * sizeof(float));
    float* mem3   = (float*)alloc((size_t)NRANK * NENT * NB * sizeof(float));
    int2*  eS     = (int2*)mem3;   // alias: eS lifetime (build..fused01) ends before mem3's (dense..final)
    float* normv  = (float*)alloc((size_t)NRANK * NB * sizeof(float));
    float* rnormv = (float*)alloc((size_t)NRANK * NB * sizeof(float));

    int cooGrid = (NTOT + 255) / 256;

    // bitmaps + fills (one memset), then single-pass ELL build
    hipMemsetAsync(bmH, 0, (2 * 1250 + 2 * NENT) * sizeof(int), stream);
    headmark_kernel<<<1, 128, 0, stream>>>(heads, bmH, bm2);
    mark2_kernel<<<cooGrid, 256, 0, stream>>>(edge_src, edge_dst, bmH, bm2);
    build_ell_kernel<<<cooGrid, 256, 0, stream>>>(edge_src, edge_dst, edge_val, bm2,
                                                  fillD, fillS, eD, eS);

    // LSTM + attention (deduped over 24 queries)
    zxq_kernel<<<6 * NQ, 128, 0, stream>>>(emb, Wih_f, bih_f, bhh_f, Wih_b, bih_b, bhh_b, zxq);
    lstmq_kernel<<<6 * NQ, 128, 0, stream>>>(Whh_f, Whh_b, zxq, hq);
    attnq_kernel<<<9, 32, 0, stream>>>(hq, W0, b0, attnq);
    expand_kernel<<<1, 256, 0, stream>>>(queries, attnq, attn);

    // steps 0+1 sparse, step 2 dense (norm fused into dense)
    hipMemsetAsync(mem2, 0, (size_t)NRANK * NENT * NB * sizeof(float), stream);
    hipMemsetAsync(normv, 0, NRANK * NB * sizeof(float), stream);
    {
        dim3 g(NB, NRANK, 2);
        fused01_kernel<<<g, 256, 0, stream>>>(heads, attn, fillS, eS, mem2);
    }
    {
        dim3 g(NPASS, NENT / 16, NRANK);
        dense_kernel<<<g, 256, 0, stream>>>(attn, fillD, eD, mem2, mem3, normv);
    }

    // epilogue
    rnorm_kernel<<<1, NRANK * NB, 0, stream>>>(normv, rnormv);
    final_kernel<<<NENT / 32, 256, 0, stream>>>(mem3, rnormv, out);
}

// Round 8
// 1443.986 us; speedup vs baseline: 4.4188x; 4.4188x over previous
//
#include <hip/hip_runtime.h>

#define NENT 40000
#define NB 128
#define NQ 24
#define NOPS 12
#define EPO 300000
#define NTOT (NOPS * EPO)
#define NRANK 3
#define NPASS 8
#define CP 16       // batch columns per pass
#define ECAP 160    // ELL row capacity (Poisson(90) max over 40K rows << 160)

typedef float v4f __attribute__((ext_vector_type(4)));

__device__ __forceinline__ v4f shfl_xor4(v4f x, int m) {
    v4f r;
    r.x = __shfl_xor(x.x, m);
    r.y = __shfl_xor(x.y, m);
    r.z = __shfl_xor(x.z, m);
    r.w = __shfl_xor(x.w, m);
    return r;
}

__device__ __forceinline__ bool bittest(const unsigned* bm, int i) {
    return (bm[i >> 5] >> (i & 31)) & 1u;
}

// ---------------- bitmaps: heads and heads ∪ N_out(heads) ----------------
__global__ void headmark_kernel(const int* __restrict__ heads, unsigned* __restrict__ bmH,
                                unsigned* __restrict__ bm2) {
    int h = heads[threadIdx.x];
    atomicOr(&bmH[h >> 5], 1u << (h & 31));
    atomicOr(&bm2[h >> 5], 1u << (h & 31));
}

__global__ void mark2_kernel(const int* __restrict__ src, const int* __restrict__ dst,
                             const unsigned* __restrict__ bmH, unsigned* __restrict__ bm2) {
    int i = blockIdx.x * 256 + threadIdx.x;
    if (i < NTOT) {
        int s = src[i];
        if (bittest(bmH, s)) {
            int d = dst[i];
            atomicOr(&bm2[d >> 5], 1u << (d & 31));
        }
    }
}

// ---------------- single-pass ELL build: dst always; src gated on bm2 ----------------
__global__ void build_ell_kernel(const int* __restrict__ src, const int* __restrict__ dst,
                                 const float* __restrict__ val, const unsigned* __restrict__ bm2,
                                 int* __restrict__ fillD, int* __restrict__ fillS,
                                 int2* __restrict__ eD, int2* __restrict__ eS) {
    int i = blockIdx.x * 256 + threadIdx.x;
    if (i >= NTOT) return;
    int s = src[i], d = dst[i];
    int op = i / EPO;   // compile-time magic-mul
    int v = __float_as_int(val[i]);
    int pd = atomicAdd(&fillD[d], 1);
    eD[(size_t)d * ECAP + pd] = make_int2(s | (op << 16), v);
    if (bittest(bm2, s)) {
        int ps = atomicAdd(&fillS[s], 1);
        eS[(size_t)s * ECAP + ps] = make_int2(d | (op << 16), v);
    }
}

// ---------------- LSTM (deduped over 24 distinct query values) ----------------
__global__ void zxq_kernel(const float* __restrict__ emb,
                           const float* __restrict__ Wih_f, const float* __restrict__ bih_f,
                           const float* __restrict__ bhh_f,
                           const float* __restrict__ Wih_b, const float* __restrict__ bih_b,
                           const float* __restrict__ bhh_b,
                           float* __restrict__ zxq) {
    int combo = blockIdx.x / NQ;
    int q = blockIdx.x % NQ;
    int dir = combo / 3, r = combo % 3;
    const float* Wih = (dir ? Wih_b : Wih_f) + r * 512 * 128;
    const float* bih = (dir ? bih_b : bih_f) + r * 512;
    const float* bhh = (dir ? bhh_b : bhh_f) + r * 512;
    __shared__ float x[128];
    int u = threadIdx.x;
    x[u] = emb[q * 128 + u];
    __syncthreads();
    const float* W0p = Wih + u * 128;
    const float* W1p = Wih + (128 + u) * 128;
    const float* W2p = Wih + (256 + u) * 128;
    const float* W3p = Wih + (384 + u) * 128;
    float a0 = 0.f, a1 = 0.f, a2 = 0.f, a3 = 0.f;
    for (int d = 0; d < 128; ++d) {
        float xv = x[d];
        a0 = fmaf(xv, W0p[d], a0);
        a1 = fmaf(xv, W1p[d], a1);
        a2 = fmaf(xv, W2p[d], a2);
        a3 = fmaf(xv, W3p[d], a3);
    }
    float* o = zxq + (size_t)(combo * NQ + q) * 512;
    o[u]       = a0 + bih[u]       + bhh[u];
    o[128 + u] = a1 + bih[128 + u] + bhh[128 + u];
    o[256 + u] = a2 + bih[256 + u] + bhh[256 + u];
    o[384 + u] = a3 + bih[384 + u] + bhh[384 + u];
}

__global__ void lstmq_kernel(const float* __restrict__ Whh_f, const float* __restrict__ Whh_b,
                             const float* __restrict__ zxq, float* __restrict__ hq) {
    int combo = blockIdx.x / NQ;
    int q = blockIdx.x % NQ;
    int dir = combo / 3, r = combo % 3;
    const float* Whh = (dir ? Whh_b : Whh_f) + r * 512 * 128;
    __shared__ float h[128];
    int u = threadIdx.x;
    const float* z = zxq + (size_t)(combo * NQ + q) * 512;
    float zi0 = z[u], zf0 = z[128 + u], zg0 = z[256 + u], zo0 = z[384 + u];
    const float* Wi = Whh + u * 128;
    const float* Wf = Whh + (128 + u) * 128;
    const float* Wg = Whh + (256 + u) * 128;
    const float* Wo = Whh + (384 + u) * 128;
    float c = 0.f;
    h[u] = 0.f;
    for (int s = 0; s < 3; ++s) {
        __syncthreads();
        float a0 = 0.f, a1 = 0.f, a2 = 0.f, a3 = 0.f;
        for (int d = 0; d < 128; ++d) {
            float hv = h[d];
            a0 = fmaf(hv, Wi[d], a0);
            a1 = fmaf(hv, Wf[d], a1);
            a2 = fmaf(hv, Wg[d], a2);
            a3 = fmaf(hv, Wo[d], a3);
        }
        float ig = 1.f / (1.f + expf(-(zi0 + a0)));
        float fg = 1.f / (1.f + expf(-(zf0 + a1)));
        float gg = tanhf(zg0 + a2);
        float og = 1.f / (1.f + expf(-(zo0 + a3)));
        c = fg * c + ig * gg;
        float hn = og * tanhf(c);
        __syncthreads();
        h[u] = hn;
        hq[(size_t)((combo * 3 + s) * NQ + q) * 128 + u] = hn;
    }
}

__global__ void attnq_kernel(const float* __restrict__ hq, const float* __restrict__ W0,
                             const float* __restrict__ b0, float* __restrict__ attnq) {
    int r = blockIdx.x / 3, t = blockIdx.x % 3;
    __shared__ float W0s[256 * 13];
    for (int idx = threadIdx.x; idx < 256 * 13; idx += 32) W0s[idx] = W0[idx];
    __syncthreads();
    int q = threadIdx.x;
    if (q >= NQ) return;
    float acc[13];
    for (int k = 0; k < 13; ++k) acc[k] = b0[k];
    const float* hf = hq + (size_t)(((0 * 3 + r) * 3 + t) * NQ + q) * 128;
    const float* hb = hq + (size_t)(((1 * 3 + r) * 3 + (2 - t)) * NQ + q) * 128;
    for (int u = 0; u < 128; ++u) {
        float v = hf[u];
        for (int k = 0; k < 13; ++k) acc[k] = fmaf(v, W0s[u * 13 + k], acc[k]);
    }
    for (int u = 0; u < 128; ++u) {
        float v = hb[u];
        for (int k = 0; k < 13; ++k) acc[k] = fmaf(v, W0s[(128 + u) * 13 + k], acc[k]);
    }
    float m = acc[0];
    for (int k = 1; k < 13; ++k) m = fmaxf(m, acc[k]);
    float e[13];
    float sum = 0.f;
    for (int k = 0; k < 13; ++k) { e[k] = expf(acc[k] - m); sum += e[k]; }
    float inv = 1.f / sum;
    float* ao = attnq + (size_t)(r * 3 + t) * 13 * NQ;
    for (int k = 0; k < 13; ++k) ao[k * NQ + q] = e[k] * inv;
}

__global__ void expand_kernel(const int* __restrict__ queries, const float* __restrict__ attnq,
                              float* __restrict__ attn) {
    __shared__ int qs[128];
    if (threadIdx.x < 128) qs[threadIdx.x] = queries[threadIdx.x];
    __syncthreads();
    for (int idx = threadIdx.x; idx < 9 * 13 * 128; idx += 256) {
        int b = idx & 127, kk = idx >> 7;
        attn[idx] = attnq[kk * NQ + qs[b]];
    }
}

// ---------------- steps 0+1, sparse expansion over ELL-S; writes pass-major mem[r][p][j][c] ----------------
// 256 threads, 8-lane groups per source entry; z-chunked grid for occupancy.
__global__ void fused01_kernel(const int* __restrict__ heads, const float* __restrict__ attn,
                               const int* __restrict__ fillS, const int2* __restrict__ eS,
                               float* __restrict__ mem2) {
    int r = blockIdx.y;
    int b = blockIdx.x;
    int chunk = blockIdx.z;   // 0..1
    __shared__ float c0s[13], c1s[13];
    if (threadIdx.x < 13) {
        c0s[threadIdx.x] = attn[(size_t)((r * 3 + 0) * 13 + threadIdx.x) * 128 + b];
        c1s[threadIdx.x] = attn[(size_t)((r * 3 + 1) * 13 + threadIdx.x) * 128 + b];
    }
    __syncthreads();
    int h = heads[b];
    int lenH = fillS[h];
    float* mem = mem2 + ((size_t)(r * NPASS + (b >> 4)) * NENT) * CP + (b & 15);
    int g = threadIdx.x >> 3, lane8 = threadIdx.x & 7;   // 32 groups of 8 lanes
    for (int ent = g + chunk * 32; ent < lenH + 1; ent += 64) {
        int i; float wv;
        if (ent == 0) { i = h; wv = c0s[12]; }
        else {
            int2 e = eS[(size_t)h * ECAP + ent - 1];
            i = e.x & 0xFFFF;
            wv = __int_as_float(e.y) * c0s[e.x >> 16];
        }
        if (lane8 == 0) atomicAdd(&mem[(size_t)i * CP], c1s[12] * wv);
        int lenI = fillS[i];
        const int2* ei = eS + (size_t)i * ECAP;
        for (int f = lane8; f < lenI; f += 8) {
            int2 e2 = ei[f];
            atomicAdd(&mem[(size_t)(e2.x & 0xFFFF) * CP],
                      __int_as_float(e2.y) * c1s[e2.x >> 16] * wv);
        }
    }
}

// ---------------- step 2: dense gather; LDS-staged edges + 3-deep pipelined gathers ----------------
struct Stage { v4f g0, g1, g2, g3; float w0, w1, w2, w3; int o0, o1, o2, o3; };

#define ISSUE_ONE(G, W, O, LT, RT, bi) { \
    bool m = (bi) < (LT); \
    int2 e = eL[RT][m ? (bi) : 0]; \
    int ex = m ? e.x : 0; \
    W = m ? __int_as_float(e.y) : 0.f; \
    O = ex >> 16; \
    G = *(const v4f*)(inr + (size_t)(ex & 0xFFFF) * CP + cq4); }

#define ISSUE(S, bb) { int bi = (bb) + slot; \
    ISSUE_ONE(S.g0, S.w0, S.o0, l0, rw + 0, bi) \
    ISSUE_ONE(S.g1, S.w1, S.o1, l1, rw + 1, bi) \
    ISSUE_ONE(S.g2, S.w2, S.o2, l2, rw + 2, bi) \
    ISSUE_ONE(S.g3, S.w3, S.o3, l3, rw + 3, bi) }

#define CONSUME(S) { \
    { v4f cc = *(const v4f*)&cs[S.o0 * 20 + cq4]; acc0 += (S.w0 * cc) * S.g0; } \
    { v4f cc = *(const v4f*)&cs[S.o1 * 20 + cq4]; acc1 += (S.w1 * cc) * S.g1; } \
    { v4f cc = *(const v4f*)&cs[S.o2 * 20 + cq4]; acc2 += (S.w2 * cc) * S.g2; } \
    { v4f cc = *(const v4f*)&cs[S.o3 * 20 + cq4]; acc3 += (S.w3 * cc) * S.g3; } }

#define REDUCE_ROW(A, T) { \
    v4f red = A; \
    red += shfl_xor4(red, 4); \
    red += shfl_xor4(red, 8); \
    red += shfl_xor4(red, 16); \
    red += shfl_xor4(red, 32); \
    if (slot == 0) { \
        int j = jw + (T); \
        v4f mi = *(const v4f*)(inr + (size_t)j * CP + cq4); \
        v4f res = cid * mi + red; \
        *(v4f*)(outr + (size_t)j * CP + cq4) = res; \
        rsum += res; \
    } }

__global__ __launch_bounds__(256) void dense_kernel(const float* __restrict__ attn,
                                                    const int* __restrict__ fillD,
                                                    const int2* __restrict__ edgesD,
                                                    const float* __restrict__ in,
                                                    float* __restrict__ out,
                                                    float* __restrict__ normv) {
    int p = blockIdx.x;   // pass = XCD (linear-id % 8 round-robin)
    int r = blockIdx.z;
    __shared__ __align__(16) float cs[13 * 20];   // stride 20 floats: rows 16B-aligned
    __shared__ float npart[4][16];
    __shared__ __align__(16) int2 eL[16][ECAP];   // 20.5 KB staged edge lists
    int tid = threadIdx.x;
    int wave = tid >> 6, lane = tid & 63;

    // async stage: 16 ELL rows = 20480 contiguous bytes, direct global->LDS, width 16
    {
        const char* gp = (const char*)(edgesD + (size_t)(blockIdx.y * 16) * ECAP);
        char* lp = (char*)&eL[0][0];
#pragma unroll
        for (int k = 0; k < 5; ++k) {
            int off = (wave * 5 + k) * 1024;
            __builtin_amdgcn_global_load_lds(
                (const __attribute__((address_space(1))) unsigned*)(gp + off + lane * 16),
                (__attribute__((address_space(3))) unsigned*)(lp + off),
                16, 0, 0);
        }
    }
    if (tid < 13 * 16) {
        int op = tid >> 4, c0 = tid & 15;
        cs[op * 20 + c0] = attn[(size_t)((r * 3 + 2) * 13 + op) * 128 + p * CP + c0];
    }
    int slot = lane >> 2;        // 16 edge slots
    int cq4 = (lane & 3) * 4;    // 4 cols per lane
    int rw = wave * 4;           // this wave's first LDS row
    int jw = blockIdx.y * 16 + rw;
    int l0 = fillD[jw], l1 = fillD[jw + 1], l2 = fillD[jw + 2], l3 = fillD[jw + 3];
    int maxlen = max(max(l0, l1), max(l2, l3));
    const float* inr = in + (size_t)(r * NPASS + p) * NENT * CP;
    float* outr = out + (size_t)(r * NPASS + p) * NENT * CP;
    __syncthreads();   // drains global_load_lds (vmcnt) + cs writes

    v4f acc0 = (v4f)0.f, acc1 = (v4f)0.f, acc2 = (v4f)0.f, acc3 = (v4f)0.f;
    Stage SA, SB, SC;
    // 3-deep software pipeline: 12 gathers continuously in flight per wave
    ISSUE(SA, 0)
    ISSUE(SB, 16)
    ISSUE(SC, 32)
    for (int base = 48; base < maxlen; base += 48) {
        CONSUME(SA) ISSUE(SA, base)
        CONSUME(SB) ISSUE(SB, base + 16)
        CONSUME(SC) ISSUE(SC, base + 32)
    }
    CONSUME(SA)
    CONSUME(SB)
    CONSUME(SC)

    v4f cid = *(const v4f*)&cs[12 * 20 + cq4];
    v4f rsum = (v4f)0.f;
    REDUCE_ROW(acc0, 0)
    REDUCE_ROW(acc1, 1)
    REDUCE_ROW(acc2, 2)
    REDUCE_ROW(acc3, 3)
    if (slot == 0) *(v4f*)&npart[wave][cq4] = rsum;
    __syncthreads();
    if (tid < 16) {
        float s = npart[0][tid] + npart[1][tid] + npart[2][tid] + npart[3][tid];
        atomicAdd(&normv[r * 128 + p * CP + tid], s);
    }
}

// ---------------- epilogue ----------------
__global__ void rnorm_kernel(const float* __restrict__ normv, float* __restrict__ rnormv) {
    int i = threadIdx.x;
    rnormv[i] = 1.f / fmaxf(normv[i], 1e-20f);
}

__global__ void final_kernel(const float* __restrict__ mem3, const float* __restrict__ rnormv,
                             float* __restrict__ out) {
    __shared__ float tile[32 * 129];
    __shared__ float rn[384];
    for (int idx = threadIdx.x; idx < 384; idx += 256) rn[idx] = rnormv[idx];
    __syncthreads();
    int j0 = blockIdx.x * 32;
    for (int p = 0; p < NPASS; ++p) {
        for (int it = 0; it < 2; ++it) {
            int lin = it * 256 + threadIdx.x;
            int jj = lin >> 4, c = lin & 15;
            int b = p * CP + c;
            float s = 0.f;
            for (int r = 0; r < 3; ++r)
                s += mem3[((size_t)(r * NPASS + p) * NENT + j0 + jj) * CP + c] * rn[r * 128 + b];
            tile[jj * 129 + b] = s;
        }
    }
    __syncthreads();
    for (int it = 0; it < 16; ++it) {
        int lin = it * 256 + threadIdx.x;
        int b = lin >> 5, jj = lin & 31;
        out[(size_t)b * NENT + j0 + jj] = tile[jj * 129 + b];
    }
}

extern "C" void kernel_launch(void* const* d_in, const int* in_sizes, int n_in,
                              void* d_out, int out_size, void* d_ws, size_t ws_size,
                              hipStream_t stream) {
    const int*   queries  = (const int*)d_in[0];
    const int*   heads    = (const int*)d_in[1];
    const int*   edge_src = (const int*)d_in[2];
    const int*   edge_dst = (const int*)d_in[3];
    const float* edge_val = (const float*)d_in[4];
    const float* emb      = (const float*)d_in[5];
    const float* Wih_f    = (const float*)d_in[6];
    const float* Whh_f    = (const float*)d_in[7];
    const float* bih_f    = (const float*)d_in[8];
    const float* bhh_f    = (const float*)d_in[9];
    const float* Wih_b    = (const float*)d_in[10];
    const float* Whh_b    = (const float*)d_in[11];
    const float* bih_b    = (const float*)d_in[12];
    const float* bhh_b    = (const float*)d_in[13];
    const float* W0       = (const float*)d_in[14];
    const float* b0       = (const float*)d_in[15];
    float* out = (float*)d_out;

    char* w = (char*)d_ws;
    size_t off = 0;
    auto alloc = [&](size_t bytes) -> void* {
        off = (off + 255) & ~(size_t)255;
        void* p = w + off;
        off += bytes;
        return p;
    };
    float* attnq  = (float*)alloc((size_t)9 * 13 * NQ * sizeof(float));
    float* attn   = (float*)alloc((size_t)9 * 13 * 128 * sizeof(float));
    float* zxq    = (float*)alloc((size_t)6 * NQ * 512 * sizeof(float));
    float* hq     = (float*)alloc((size_t)6 * 3 * NQ * 128 * sizeof(float));
    // meta block (single memset): bmH | bm2 | fillD | fillS
    unsigned* bmH = (unsigned*)alloc((2 * 1250 + 2 * NENT) * sizeof(int));
    unsigned* bm2 = bmH + 1250;
    int* fillD    = (int*)(bm2 + 1250);
    int* fillS    = fillD + NENT;
    int2*  eD     = (int2*)alloc((size_t)NENT * ECAP * sizeof(int2));
    float* mem2   = (float*)alloc((size_t)NRANK * NENT * NB * sizeof(float));
    float* mem3   = (float*)alloc((size_t)NRANK * NENT * NB * sizeof(float));
    int2*  eS     = (int2*)mem3;   // alias: eS lifetime (build..fused01) ends before mem3's (dense..final)
    float* normv  = (float*)alloc((size_t)NRANK * NB * sizeof(float));
    float* rnormv = (float*)alloc((size_t)NRANK * NB * sizeof(float));

    int cooGrid = (NTOT + 255) / 256;

    // bitmaps + fills (one memset), then single-pass ELL build
    hipMemsetAsync(bmH, 0, (2 * 1250 + 2 * NENT) * sizeof(int), stream);
    headmark_kernel<<<1, 128, 0, stream>>>(heads, bmH, bm2);
    mark2_kernel<<<cooGrid, 256, 0, stream>>>(edge_src, edge_dst, bmH, bm2);
    build_ell_kernel<<<cooGrid, 256, 0, stream>>>(edge_src, edge_dst, edge_val, bm2,
                                                  fillD, fillS, eD, eS);

    // LSTM + attention (deduped over 24 queries)
    zxq_kernel<<<6 * NQ, 128, 0, stream>>>(emb, Wih_f, bih_f, bhh_f, Wih_b, bih_b, bhh_b, zxq);
    lstmq_kernel<<<6 * NQ, 128, 0, stream>>>(Whh_f, Whh_b, zxq, hq);
    attnq_kernel<<<9, 32, 0, stream>>>(hq, W0, b0, attnq);
    expand_kernel<<<1, 256, 0, stream>>>(queries, attnq, attn);

    // steps 0+1 sparse, step 2 dense (norm fused into dense)
    hipMemsetAsync(mem2, 0, (size_t)NRANK * NENT * NB * sizeof(float), stream);
    hipMemsetAsync(normv, 0, NRANK * NB * sizeof(float), stream);
    {
        dim3 g(NB, NRANK, 2);
        fused01_kernel<<<g, 256, 0, stream>>>(heads, attn, fillS, eS, mem2);
    }
    {
        dim3 g(NPASS, NENT / 16, NRANK);
        dense_kernel<<<g, 256, 0, stream>>>(attn, fillD, eD, mem2, mem3, normv);
    }

    // epilogue
    rnorm_kernel<<<1, NRANK * NB, 0, stream>>>(normv, rnormv);
    final_kernel<<<NENT / 32, 256, 0, stream>>>(mem3, rnormv, out);
}

// Round 9
// 1271.084 us; speedup vs baseline: 5.0199x; 1.1360x over previous
//
#include <hip/hip_runtime.h>

#define NENT 40000
#define NB 128
#define NQ 24
#define NOPS 12
#define EPO 300000
#define NTOT (NOPS * EPO)
#define NRANK 3
#define NPASS 8
#define CP 16       // batch columns per pass
#define ECAP 160    // ELL row capacity (Poisson(90) max over 40K rows << 160)

typedef float v4f __attribute__((ext_vector_type(4)));

__device__ __forceinline__ v4f shfl_xor4(v4f x, int m) {
    v4f r;
    r.x = __shfl_xor(x.x, m);
    r.y = __shfl_xor(x.y, m);
    r.z = __shfl_xor(x.z, m);
    r.w = __shfl_xor(x.w, m);
    return r;
}

__device__ __forceinline__ bool bittest(const unsigned* bm, int i) {
    return (bm[i >> 5] >> (i & 31)) & 1u;
}

// ---------------- bitmaps: heads and heads ∪ N_out(heads) ----------------
__global__ void headmark_kernel(const int* __restrict__ heads, unsigned* __restrict__ bmH,
                                unsigned* __restrict__ bm2) {
    int h = heads[threadIdx.x];
    atomicOr(&bmH[h >> 5], 1u << (h & 31));
    atomicOr(&bm2[h >> 5], 1u << (h & 31));
}

__global__ void mark2_kernel(const int* __restrict__ src, const int* __restrict__ dst,
                             const unsigned* __restrict__ bmH, unsigned* __restrict__ bm2) {
    int i = blockIdx.x * 256 + threadIdx.x;
    if (i < NTOT) {
        int s = src[i];
        if (bittest(bmH, s)) {
            int d = dst[i];
            atomicOr(&bm2[d >> 5], 1u << (d & 31));
        }
    }
}

// ---------------- single-pass ELL build: dst always; src gated on bm2 ----------------
__global__ void build_ell_kernel(const int* __restrict__ src, const int* __restrict__ dst,
                                 const float* __restrict__ val, const unsigned* __restrict__ bm2,
                                 int* __restrict__ fillD, int* __restrict__ fillS,
                                 int2* __restrict__ eD, int2* __restrict__ eS) {
    int i = blockIdx.x * 256 + threadIdx.x;
    if (i >= NTOT) return;
    int s = src[i], d = dst[i];
    int op = i / EPO;   // compile-time magic-mul
    int v = __float_as_int(val[i]);
    int pd = atomicAdd(&fillD[d], 1);
    eD[(size_t)d * ECAP + pd] = make_int2(s | (op << 16), v);
    if (bittest(bm2, s)) {
        int ps = atomicAdd(&fillS[s], 1);
        eS[(size_t)s * ECAP + ps] = make_int2(d | (op << 16), v);
    }
}

// ---------------- LSTM (deduped over 24 distinct query values) ----------------
__global__ void zxq_kernel(const float* __restrict__ emb,
                           const float* __restrict__ Wih_f, const float* __restrict__ bih_f,
                           const float* __restrict__ bhh_f,
                           const float* __restrict__ Wih_b, const float* __restrict__ bih_b,
                           const float* __restrict__ bhh_b,
                           float* __restrict__ zxq) {
    int combo = blockIdx.x / NQ;
    int q = blockIdx.x % NQ;
    int dir = combo / 3, r = combo % 3;
    const float* Wih = (dir ? Wih_b : Wih_f) + r * 512 * 128;
    const float* bih = (dir ? bih_b : bih_f) + r * 512;
    const float* bhh = (dir ? bhh_b : bhh_f) + r * 512;
    __shared__ float x[128];
    int u = threadIdx.x;
    x[u] = emb[q * 128 + u];
    __syncthreads();
    const float* W0p = Wih + u * 128;
    const float* W1p = Wih + (128 + u) * 128;
    const float* W2p = Wih + (256 + u) * 128;
    const float* W3p = Wih + (384 + u) * 128;
    float a0 = 0.f, a1 = 0.f, a2 = 0.f, a3 = 0.f;
    for (int d = 0; d < 128; ++d) {
        float xv = x[d];
        a0 = fmaf(xv, W0p[d], a0);
        a1 = fmaf(xv, W1p[d], a1);
        a2 = fmaf(xv, W2p[d], a2);
        a3 = fmaf(xv, W3p[d], a3);
    }
    float* o = zxq + (size_t)(combo * NQ + q) * 512;
    o[u]       = a0 + bih[u]       + bhh[u];
    o[128 + u] = a1 + bih[128 + u] + bhh[128 + u];
    o[256 + u] = a2 + bih[256 + u] + bhh[256 + u];
    o[384 + u] = a3 + bih[384 + u] + bhh[384 + u];
}

__global__ void lstmq_kernel(const float* __restrict__ Whh_f, const float* __restrict__ Whh_b,
                             const float* __restrict__ zxq, float* __restrict__ hq) {
    int combo = blockIdx.x / NQ;
    int q = blockIdx.x % NQ;
    int dir = combo / 3, r = combo % 3;
    const float* Whh = (dir ? Whh_b : Whh_f) + r * 512 * 128;
    __shared__ float h[128];
    int u = threadIdx.x;
    const float* z = zxq + (size_t)(combo * NQ + q) * 512;
    float zi0 = z[u], zf0 = z[128 + u], zg0 = z[256 + u], zo0 = z[384 + u];
    const float* Wi = Whh + u * 128;
    const float* Wf = Whh + (128 + u) * 128;
    const float* Wg = Whh + (256 + u) * 128;
    const float* Wo = Whh + (384 + u) * 128;
    float c = 0.f;
    h[u] = 0.f;
    for (int s = 0; s < 3; ++s) {
        __syncthreads();
        float a0 = 0.f, a1 = 0.f, a2 = 0.f, a3 = 0.f;
        for (int d = 0; d < 128; ++d) {
            float hv = h[d];
            a0 = fmaf(hv, Wi[d], a0);
            a1 = fmaf(hv, Wf[d], a1);
            a2 = fmaf(hv, Wg[d], a2);
            a3 = fmaf(hv, Wo[d], a3);
        }
        float ig = 1.f / (1.f + expf(-(zi0 + a0)));
        float fg = 1.f / (1.f + expf(-(zf0 + a1)));
        float gg = tanhf(zg0 + a2);
        float og = 1.f / (1.f + expf(-(zo0 + a3)));
        c = fg * c + ig * gg;
        float hn = og * tanhf(c);
        __syncthreads();
        h[u] = hn;
        hq[(size_t)((combo * 3 + s) * NQ + q) * 128 + u] = hn;
    }
}

__global__ void attnq_kernel(const float* __restrict__ hq, const float* __restrict__ W0,
                             const float* __restrict__ b0, float* __restrict__ attnq) {
    int r = blockIdx.x / 3, t = blockIdx.x % 3;
    __shared__ float W0s[256 * 13];
    for (int idx = threadIdx.x; idx < 256 * 13; idx += 32) W0s[idx] = W0[idx];
    __syncthreads();
    int q = threadIdx.x;
    if (q >= NQ) return;
    float acc[13];
    for (int k = 0; k < 13; ++k) acc[k] = b0[k];
    const float* hf = hq + (size_t)(((0 * 3 + r) * 3 + t) * NQ + q) * 128;
    const float* hb = hq + (size_t)(((1 * 3 + r) * 3 + (2 - t)) * NQ + q) * 128;
    for (int u = 0; u < 128; ++u) {
        float v = hf[u];
        for (int k = 0; k < 13; ++k) acc[k] = fmaf(v, W0s[u * 13 + k], acc[k]);
    }
    for (int u = 0; u < 128; ++u) {
        float v = hb[u];
        for (int k = 0; k < 13; ++k) acc[k] = fmaf(v, W0s[(128 + u) * 13 + k], acc[k]);
    }
    float m = acc[0];
    for (int k = 1; k < 13; ++k) m = fmaxf(m, acc[k]);
    float e[13];
    float sum = 0.f;
    for (int k = 0; k < 13; ++k) { e[k] = expf(acc[k] - m); sum += e[k]; }
    float inv = 1.f / sum;
    float* ao = attnq + (size_t)(r * 3 + t) * 13 * NQ;
    for (int k = 0; k < 13; ++k) ao[k * NQ + q] = e[k] * inv;
}

__global__ void expand_kernel(const int* __restrict__ queries, const float* __restrict__ attnq,
                              float* __restrict__ attn) {
    __shared__ int qs[128];
    if (threadIdx.x < 128) qs[threadIdx.x] = queries[threadIdx.x];
    __syncthreads();
    for (int idx = threadIdx.x; idx < 9 * 13 * 128; idx += 256) {
        int b = idx & 127, kk = idx >> 7;
        attn[idx] = attnq[kk * NQ + qs[b]];
    }
}

// ---------------- steps 0+1, sparse expansion over ELL-S; writes pass-major mem[r][p][j][c] ----------------
// 256 threads, 8-lane groups per source entry; z-chunked grid for occupancy.
__global__ void fused01_kernel(const int* __restrict__ heads, const float* __restrict__ attn,
                               const int* __restrict__ fillS, const int2* __restrict__ eS,
                               float* __restrict__ mem2) {
    int r = blockIdx.y;
    int b = blockIdx.x;
    int chunk = blockIdx.z;   // 0..1
    __shared__ float c0s[13], c1s[13];
    if (threadIdx.x < 13) {
        c0s[threadIdx.x] = attn[(size_t)((r * 3 + 0) * 13 + threadIdx.x) * 128 + b];
        c1s[threadIdx.x] = attn[(size_t)((r * 3 + 1) * 13 + threadIdx.x) * 128 + b];
    }
    __syncthreads();
    int h = heads[b];
    int lenH = fillS[h];
    float* mem = mem2 + ((size_t)(r * NPASS + (b >> 4)) * NENT) * CP + (b & 15);
    int g = threadIdx.x >> 3, lane8 = threadIdx.x & 7;   // 32 groups of 8 lanes
    for (int ent = g + chunk * 32; ent < lenH + 1; ent += 64) {
        int i; float wv;
        if (ent == 0) { i = h; wv = c0s[12]; }
        else {
            int2 e = eS[(size_t)h * ECAP + ent - 1];
            i = e.x & 0xFFFF;
            wv = __int_as_float(e.y) * c0s[e.x >> 16];
        }
        if (lane8 == 0) atomicAdd(&mem[(size_t)i * CP], c1s[12] * wv);
        int lenI = fillS[i];
        const int2* ei = eS + (size_t)i * ECAP;
        for (int f = lane8; f < lenI; f += 8) {
            int2 e2 = ei[f];
            atomicAdd(&mem[(size_t)(e2.x & 0xFFFF) * CP],
                      __int_as_float(e2.y) * c1s[e2.x >> 16] * wv);
        }
    }
}

// ---------------- step 2: dense gather; 3-stage register pipeline (16-slot stages) ----------------
// Rotation per phase: consume G_s -> issue E_s(+48) -> issue G_{s+2}. Edge loads get ~1 phase,
// gathers ~2 phases of latency cover; ~8-12 loads in flight per wave at baseline occupancy.
struct EStage { int2 a, b, c, d; };
struct GStage { v4f a, b, c, d; };

#define ISSUE_E(E, bb) { int bi = (bb) + slot; \
    E.a = edp0[bi < l0 ? bi : 0]; \
    E.b = edp1[bi < l1 ? bi : 0]; \
    E.c = edp2[bi < l2 ? bi : 0]; \
    E.d = edp3[bi < l3 ? bi : 0]; }

#define ISSUE_G(G, E) { \
    G.a = *(const v4f*)(inr + (size_t)(E.a.x & 0xFFFF) * CP + cq4); \
    G.b = *(const v4f*)(inr + (size_t)(E.b.x & 0xFFFF) * CP + cq4); \
    G.c = *(const v4f*)(inr + (size_t)(E.c.x & 0xFFFF) * CP + cq4); \
    G.d = *(const v4f*)(inr + (size_t)(E.d.x & 0xFFFF) * CP + cq4); }

#define CONSUME_P(G, E, bb) { int bi = (bb) + slot; \
    { v4f cc = *(const v4f*)&cs[(E.a.x >> 16) * 20 + cq4]; \
      float w = bi < l0 ? __int_as_float(E.a.y) : 0.f; acc0 += (w * cc) * G.a; } \
    { v4f cc = *(const v4f*)&cs[(E.b.x >> 16) * 20 + cq4]; \
      float w = bi < l1 ? __int_as_float(E.b.y) : 0.f; acc1 += (w * cc) * G.b; } \
    { v4f cc = *(const v4f*)&cs[(E.c.x >> 16) * 20 + cq4]; \
      float w = bi < l2 ? __int_as_float(E.c.y) : 0.f; acc2 += (w * cc) * G.c; } \
    { v4f cc = *(const v4f*)&cs[(E.d.x >> 16) * 20 + cq4]; \
      float w = bi < l3 ? __int_as_float(E.d.y) : 0.f; acc3 += (w * cc) * G.d; } }

#define REDUCE_ROW(A, T) { \
    v4f red = A; \
    red += shfl_xor4(red, 4); \
    red += shfl_xor4(red, 8); \
    red += shfl_xor4(red, 16); \
    red += shfl_xor4(red, 32); \
    if (slot == 0) { \
        int j = jw + (T); \
        v4f mi = *(const v4f*)(inr + (size_t)j * CP + cq4); \
        v4f res = cid * mi + red; \
        *(v4f*)(outr + (size_t)j * CP + cq4) = res; \
        rsum += res; \
    } }

__global__ __launch_bounds__(256) void dense_kernel(const float* __restrict__ attn,
                                                    const int* __restrict__ fillD,
                                                    const int2* __restrict__ edgesD,
                                                    const float* __restrict__ in,
                                                    float* __restrict__ out,
                                                    float* __restrict__ normv) {
    int p = blockIdx.x;   // pass = XCD (linear-id % 8 round-robin)
    int r = blockIdx.z;
    __shared__ __align__(16) float cs[13 * 20];   // stride 20 floats: rows 16B-aligned
    __shared__ float npart[4][16];
    int tid = threadIdx.x;
    if (tid < 13 * 16) {
        int op = tid >> 4, c0 = tid & 15;
        cs[op * 20 + c0] = attn[(size_t)((r * 3 + 2) * 13 + op) * 128 + p * CP + c0];
    }
    __syncthreads();
    int wave = tid >> 6, lane = tid & 63;
    int slot = lane >> 2;        // 16 edge slots
    int cq4 = (lane & 3) * 4;    // 4 cols per lane
    int jw = blockIdx.y * 16 + wave * 4;   // 4 rows per wave
    const float* inr = in + (size_t)(r * NPASS + p) * NENT * CP;
    float* outr = out + (size_t)(r * NPASS + p) * NENT * CP;
    int l0 = fillD[jw], l1 = fillD[jw + 1], l2 = fillD[jw + 2], l3 = fillD[jw + 3];
    const int2* edp0 = edgesD + (size_t)(jw + 0) * ECAP;
    const int2* edp1 = edgesD + (size_t)(jw + 1) * ECAP;
    const int2* edp2 = edgesD + (size_t)(jw + 2) * ECAP;
    const int2* edp3 = edgesD + (size_t)(jw + 3) * ECAP;
    int maxlen = max(max(l0, l1), max(l2, l3));
    v4f acc0 = (v4f)0.f, acc1 = (v4f)0.f, acc2 = (v4f)0.f, acc3 = (v4f)0.f;

    EStage E0, E1, E2;
    GStage G0, G1, G2;
    // prologue: invariant at loop entry = {E0,E1,E2 hold blocks base,+16,+32; G0,G1 issued}
    ISSUE_E(E0, 0)
    ISSUE_E(E1, 16)
    ISSUE_E(E2, 32)
    ISSUE_G(G0, E0)
    ISSUE_G(G1, E1)
    int nb = (maxlen + 15) >> 4;     // 16-slot blocks (masked overrun is free)
    int R = (nb + 2) / 3;            // rotation rounds
    int base = 0;
    for (int rr = 0; rr < R; ++rr, base += 48) {
        CONSUME_P(G0, E0, base)          // block base+0
        ISSUE_E(E0, base + 48)
        ISSUE_G(G2, E2)                  // block base+32
        CONSUME_P(G1, E1, base + 16)     // block base+16
        ISSUE_E(E1, base + 64)
        ISSUE_G(G0, E0)                  // block base+48
        CONSUME_P(G2, E2, base + 32)     // block base+32
        ISSUE_E(E2, base + 80)
        ISSUE_G(G1, E1)                  // block base+64
    }
    // in-flight G0/G1 past nb are fully masked; safe to drop.

    v4f cid = *(const v4f*)&cs[12 * 20 + cq4];
    v4f rsum = (v4f)0.f;
    REDUCE_ROW(acc0, 0)
    REDUCE_ROW(acc1, 1)
    REDUCE_ROW(acc2, 2)
    REDUCE_ROW(acc3, 3)
    if (slot == 0) *(v4f*)&npart[wave][cq4] = rsum;
    __syncthreads();
    if (tid < 16) {
        float s = npart[0][tid] + npart[1][tid] + npart[2][tid] + npart[3][tid];
        atomicAdd(&normv[r * 128 + p * CP + tid], s);
    }
}

// ---------------- epilogue ----------------
__global__ void rnorm_kernel(const float* __restrict__ normv, float* __restrict__ rnormv) {
    int i = threadIdx.x;
    rnormv[i] = 1.f / fmaxf(normv[i], 1e-20f);
}

__global__ void final_kernel(const float* __restrict__ mem3, const float* __restrict__ rnormv,
                             float* __restrict__ out) {
    __shared__ float tile[32 * 129];
    __shared__ float rn[384];
    for (int idx = threadIdx.x; idx < 384; idx += 256) rn[idx] = rnormv[idx];
    __syncthreads();
    int j0 = blockIdx.x * 32;
    for (int p = 0; p < NPASS; ++p) {
        for (int it = 0; it < 2; ++it) {
            int lin = it * 256 + threadIdx.x;
            int jj = lin >> 4, c = lin & 15;
            int b = p * CP + c;
            float s = 0.f;
            for (int r = 0; r < 3; ++r)
                s += mem3[((size_t)(r * NPASS + p) * NENT + j0 + jj) * CP + c] * rn[r * 128 + b];
            tile[jj * 129 + b] = s;
        }
    }
    __syncthreads();
    for (int it = 0; it < 16; ++it) {
        int lin = it * 256 + threadIdx.x;
        int b = lin >> 5, jj = lin & 31;
        out[(size_t)b * NENT + j0 + jj] = tile[jj * 129 + b];
    }
}

extern "C" void kernel_launch(void* const* d_in, const int* in_sizes, int n_in,
                              void* d_out, int out_size, void* d_ws, size_t ws_size,
                              hipStream_t stream) {
    const int*   queries  = (const int*)d_in[0];
    const int*   heads    = (const int*)d_in[1];
    const int*   edge_src = (const int*)d_in[2];
    const int*   edge_dst = (const int*)d_in[3];
    const float* edge_val = (const float*)d_in[4];
    const float* emb      = (const float*)d_in[5];
    const float* Wih_f    = (const float*)d_in[6];
    const float* Whh_f    = (const float*)d_in[7];
    const float* bih_f    = (const float*)d_in[8];
    const float* bhh_f    = (const float*)d_in[9];
    const float* Wih_b    = (const float*)d_in[10];
    const float* Whh_b    = (const float*)d_in[11];
    const float* bih_b    = (const float*)d_in[12];
    const float* bhh_b    = (const float*)d_in[13];
    const float* W0       = (const float*)d_in[14];
    const float* b0       = (const float*)d_in[15];
    float* out = (float*)d_out;

    char* w = (char*)d_ws;
    size_t off = 0;
    auto alloc = [&](size_t bytes) -> void* {
        off = (off + 255) & ~(size_t)255;
        void* p = w + off;
        off += bytes;
        return p;
    };
    float* attnq  = (float*)alloc((size_t)9 * 13 * NQ * sizeof(float));
    float* attn   = (float*)alloc((size_t)9 * 13 * 128 * sizeof(float));
    float* zxq    = (float*)alloc((size_t)6 * NQ * 512 * sizeof(float));
    float* hq     = (float*)alloc((size_t)6 * 3 * NQ * 128 * sizeof(float));
    // meta block (single memset): bmH | bm2 | fillD | fillS
    unsigned* bmH = (unsigned*)alloc((2 * 1250 + 2 * NENT) * sizeof(int));
    unsigned* bm2 = bmH + 1250;
    int* fillD    = (int*)(bm2 + 1250);
    int* fillS    = fillD + NENT;
    int2*  eD     = (int2*)alloc((size_t)NENT * ECAP * sizeof(int2));
    float* mem2   = (float*)alloc((size_t)NRANK * NENT * NB * sizeof(float));
    float* mem3   = (float*)alloc((size_t)NRANK * NENT * NB * sizeof(float));
    int2*  eS     = (int2*)mem3;   // alias: eS lifetime (build..fused01) ends before mem3's (dense..final)
    float* normv  = (float*)alloc((size_t)NRANK * NB * sizeof(float));
    float* rnormv = (float*)alloc((size_t)NRANK * NB * sizeof(float));

    int cooGrid = (NTOT + 255) / 256;

    // bitmaps + fills (one memset), then single-pass ELL build
    hipMemsetAsync(bmH, 0, (2 * 1250 + 2 * NENT) * sizeof(int), stream);
    headmark_kernel<<<1, 128, 0, stream>>>(heads, bmH, bm2);
    mark2_kernel<<<cooGrid, 256, 0, stream>>>(edge_src, edge_dst, bmH, bm2);
    build_ell_kernel<<<cooGrid, 256, 0, stream>>>(edge_src, edge_dst, edge_val, bm2,
                                                  fillD, fillS, eD, eS);

    // LSTM + attention (deduped over 24 queries)
    zxq_kernel<<<6 * NQ, 128, 0, stream>>>(emb, Wih_f, bih_f, bhh_f, Wih_b, bih_b, bhh_b, zxq);
    lstmq_kernel<<<6 * NQ, 128, 0, stream>>>(Whh_f, Whh_b, zxq, hq);
    attnq_kernel<<<9, 32, 0, stream>>>(hq, W0, b0, attnq);
    expand_kernel<<<1, 256, 0, stream>>>(queries, attnq, attn);

    // steps 0+1 sparse, step 2 dense (norm fused into dense)
    hipMemsetAsync(mem2, 0, (size_t)NRANK * NENT * NB * sizeof(float), stream);
    hipMemsetAsync(normv, 0, NRANK * NB * sizeof(float), stream);
    {
        dim3 g(NB, NRANK, 2);
        fused01_kernel<<<g, 256, 0, stream>>>(heads, attn, fillS, eS, mem2);
    }
    {
        dim3 g(NPASS, NENT / 16, NRANK);
        dense_kernel<<<g, 256, 0, stream>>>(attn, fillD, eD, mem2, mem3, normv);
    }

    // epilogue
    rnorm_kernel<<<1, NRANK * NB, 0, stream>>>(normv, rnormv);
    final_kernel<<<NENT / 32, 256, 0, stream>>>(mem3, rnormv, out);
}